// Round 11
// baseline (196.211 us; speedup 1.0000x reference)
//
#include <hip/hip_runtime.h>
#include <stdint.h>

typedef __bf16 bf16;
typedef __bf16 bf16x8 __attribute__((ext_vector_type(8)));
typedef float f32x4 __attribute__((ext_vector_type(4)));

struct alignas(8) U16x4 { uint16_t v[4]; };
struct alignas(16) U16x8 { uint16_t v[8]; };

__device__ __forceinline__ f32x4 mfma16(bf16x8 a, bf16x8 b, f32x4 c) {
    return __builtin_amdgcn_mfma_f32_16x16x32_bf16(a, b, c, 0, 0, 0);
}

__device__ __forceinline__ void gload_lds16(const void* g, void* l) {
    __builtin_amdgcn_global_load_lds(
        (const __attribute__((address_space(1))) uint32_t*)g,
        (__attribute__((address_space(3))) uint32_t*)l, 16, 0, 0);
}

__device__ __forceinline__ uint16_t bf_bits(bf16 v) {
    return __builtin_bit_cast(uint16_t, v);
}

__device__ __forceinline__ float bf2f(uint16_t u) {
    uint32_t x = (uint32_t)u << 16;
    return __builtin_bit_cast(float, x);
}

// Q pre-scale: 1/sqrt(64) * log2(e), so attention works in exp2 domain.
#define QSCALE 0.18033688011112042f

// ---------------------------------------------------------------------------
// Projection: out = x @ W + b, with W transposed f32->bf16 fragment-major
// straight into LDS in the prologue (wprep folded in; W is L2-hot).
// BM=64, 256 threads (4 waves x 16 rows), grid 256x3 = 768 blocks = 3/CU.
// A-fragments direct from global with depth-8 static prefetch.
// q pre-scaled by QSCALE. v stored transposed [8][64][2048].
// Block (0,0) also zeroes the attn combine counters (runs before attn).
// ---------------------------------------------------------------------------
__global__ __launch_bounds__(256, 2)
void proj_kernel(const float* __restrict__ xq, const float* __restrict__ xk,
                 const float* __restrict__ xv,
                 const float* __restrict__ Wq, const float* __restrict__ bq,
                 const float* __restrict__ Wk, const float* __restrict__ bk,
                 const float* __restrict__ Wv, const float* __restrict__ bv,
                 uint16_t* __restrict__ q_ws, uint16_t* __restrict__ k_ws,
                 uint16_t* __restrict__ vt_ws, uint32_t* __restrict__ cnt)
{
    const int p = blockIdx.y;
    const float* x    = (p == 0) ? xq : (p == 1) ? xk : xv;
    const float* W    = (p == 0) ? Wq : (p == 1) ? Wk : Wv;
    const float* bias = (p == 0) ? bq : (p == 1) ? bk : bv;

    const int m0 = blockIdx.x * 64;
    const int t  = threadIdx.x;
    const int l  = t & 63;
    const int w  = t >> 6;           // 0..3

    __shared__ __align__(16) uint16_t sW[32768];   // 64 KB: [kt][f][l] bf16x8

    if (blockIdx.x == 0 && p == 0 && t < 128) cnt[t] = 0;

    const int arow = m0 + w * 16 + (l & 15);       // this lane's A-frag row
    const int kg   = (l >> 4) * 8;                 // k sub-offset in 32-step
    const float* xrow = x + (size_t)arow * 512 + kg;

    // ---- A prefetch prologue: depth 8 (16 loads in flight per lane)
    float4 av0[8], av1[8];
    #pragma unroll
    for (int s = 0; s < 8; s++) {
        av0[s] = *(const float4*)(xrow + s * 32);
        av1[s] = *(const float4*)(xrow + s * 32 + 4);
    }

    // ---- transpose W f32 -> bf16x8 fragments in LDS (wprep's index map):
    // chunk c = r*256 + t -> kt=r, f=(t>>6)&3, lane=t&63;
    // n=(lane&15)+16f, k0=kt*32+((lane>>4)&3)*8.
    {
        const int f2 = (t >> 6) & 3;
        const int n  = (t & 15) + 16 * f2;
        const int kq = ((t >> 4) & 3) * 8;
        #pragma unroll 4
        for (int r = 0; r < 16; r++) {
            const int k0 = r * 32 + kq;
            bf16x8 v;
            #pragma unroll
            for (int j = 0; j < 8; j++)
                v[j] = (bf16)W[(size_t)(k0 + j) * 64 + n];
            *(bf16x8*)((char*)sW + (r * 256 + t) * 16) = v;
        }
    }

    __syncthreads();

    f32x4 acc[4];
    const f32x4 zero = {0.f, 0.f, 0.f, 0.f};
    #pragma unroll
    for (int f = 0; f < 4; f++) acc[f] = zero;

    #pragma unroll
    for (int kt = 0; kt < 16; kt++) {
        const int slot = kt & 7;
        bf16x8 a;
        a[0] = (bf16)av0[slot].x; a[1] = (bf16)av0[slot].y;
        a[2] = (bf16)av0[slot].z; a[3] = (bf16)av0[slot].w;
        a[4] = (bf16)av1[slot].x; a[5] = (bf16)av1[slot].y;
        a[6] = (bf16)av1[slot].z; a[7] = (bf16)av1[slot].w;
        if (kt < 8) {
            const int kb = (kt + 8) * 32;
            av0[slot] = *(const float4*)(xrow + kb);
            av1[slot] = *(const float4*)(xrow + kb + 4);
        }
        #pragma unroll
        for (int f = 0; f < 4; f++) {
            bf16x8 bfr = *(const bf16x8*)((const char*)sW + ((kt * 4 + f) * 64 + l) * 16);
            acc[f] = mfma16(a, bfr, acc[f]);
        }
    }

    float bv4[4];
    #pragma unroll
    for (int f = 0; f < 4; f++) bv4[f] = bias[16 * f + (l & 15)];

    if (p < 2) {
        uint16_t* outp = (p == 0) ? q_ws : k_ws;
        const float scale = (p == 0) ? QSCALE : 1.0f;
        #pragma unroll
        for (int f = 0; f < 4; f++)
            #pragma unroll
            for (int r = 0; r < 4; r++) {
                const int row = m0 + w * 16 + (l >> 4) * 4 + r;
                const int col = 16 * f + (l & 15);
                outp[(size_t)row * 64 + col] = bf_bits((bf16)((acc[f][r] + bv4[f]) * scale));
            }
    } else {
        #pragma unroll
        for (int f = 0; f < 4; f++) {
            const int row0 = m0 + w * 16 + (l >> 4) * 4;
            const int col  = 16 * f + (l & 15);
            const int bb = row0 >> 11;
            const int s0 = row0 & 2047;
            U16x4 pk;
            #pragma unroll
            for (int r = 0; r < 4; r++)
                pk.v[r] = bf_bits((bf16)(acc[f][r] + bv4[f]));
            *(U16x4*)(vt_ws + ((size_t)bb * 64 + col) * 2048 + s0) = pk;
        }
    }
}

// ---------------------------------------------------------------------------
// Flash attention, SWAPPED QK^T (lane holds S[kv][q]; softmax = 15 reg-max +
// 2 shfl). NCHUNK=4: grid (16,8,4)=512 blocks. KV tiles of 64, double-
// buffered gload_lds with pre-swizzled source. Exact defer-rescale.
// Fastest-finisher combine: after writing bf16 partials + (m,l), the last
// block per (b,qt) (device-scope atomic counter) merges all chunks -> out.
// ---------------------------------------------------------------------------
template <int NCHUNK>
__global__ __launch_bounds__(512, 4)
void attn_kernel(const uint16_t* __restrict__ q_ws, const uint16_t* __restrict__ k_ws,
                 const uint16_t* __restrict__ vt_ws, float* __restrict__ out,
                 uint16_t* __restrict__ O_part, float* __restrict__ m_arr,
                 float* __restrict__ l_arr, uint32_t* __restrict__ cnt)
{
    constexpr int NT = 32 / NCHUNK;  // KV tiles per chunk
    const int qt = blockIdx.x, b = blockIdx.y, c = blockIdx.z;
    const int t = threadIdx.x, l = t & 63, w = t >> 6;   // w: 0..7
    const int q = l & 15, g = l >> 4;
    const int q0 = qt * 128;

    __shared__ __align__(16) uint16_t sK[2][64 * 64];  // [s][d] swizzled
    __shared__ __align__(16) uint16_t sV[2][64 * 64];  // [dv][s] swizzled
    __shared__ __align__(16) uint16_t sP[8][16 * 64];  // per-wave P [q][kv], swizzled
    __shared__ uint32_t s_old;

    const uint16_t* qp = q_ws + ((size_t)(b * 2048 + q0)) * 64;
    const uint16_t* kp = k_ws + (size_t)b * 2048 * 64;
    const uint16_t* vp = vt_ws + (size_t)b * 64 * 2048;

    // Q fragments (pre-scaled: scores come out in log2 units)
    bf16x8 aq[2];
    #pragma unroll
    for (int ks = 0; ks < 2; ks++)
        aq[ks] = *(const bf16x8*)(qp + (size_t)(w * 16 + q) * 64 + g * 8 + ks * 32);

    const f32x4 zero = {0.f, 0.f, 0.f, 0.f};
    f32x4 acco[4];
    #pragma unroll
    for (int f = 0; f < 4; f++) acco[f] = zero;
    float m_st = -__builtin_inff();   // running max for this q-row
    float l_st = 0.f;                 // running sum for this q-row

    // 512 threads: thread t stages one 16B chunk of K and one of V.
    auto stage = [&](int tile, int buf) {
        const int kv0  = tile * 64;
        const int row  = t >> 3;                    // 0..63
        const int slot = (t & 7) ^ (row & 7);       // inverse swizzle on source
        gload_lds16(kp + (size_t)(kv0 + row) * 64 + slot * 8,
                    (char*)sK[buf] + t * 16);
        gload_lds16(vp + (size_t)row * 2048 + kv0 + slot * 8,
                    (char*)sV[buf] + t * 16);
    };

    stage(c * NT, 0);
    __syncthreads();

    for (int i = 0; i < NT; i++) {
        const int buf = i & 1;
        if (i < NT - 1) stage(c * NT + i + 1, buf ^ 1);

        // ---- scores, swapped: accs[f][r] = S[kv=f*16+g*4+r][q]  (log2 dom.)
        f32x4 accs[4];
        #pragma unroll
        for (int f = 0; f < 4; f++) accs[f] = zero;
        #pragma unroll
        for (int ks = 0; ks < 2; ks++) {
            const int kb = g * 16 + ks * 64;
            #pragma unroll
            for (int f = 0; f < 4; f++) {
                const int srow = q + 16 * f;   // kv row in LDS
                bf16x8 bk = *(const bf16x8*)((const char*)sK[buf] + srow * 128 + (kb ^ ((srow & 7) << 4)));
                accs[f] = mfma16(bk, aq[ks], accs[f]);   // A=K, B=Q
            }
        }

        // ---- per-lane softmax over 16 regs + 4-lane butterfly
        float mx = accs[0][0];
        #pragma unroll
        for (int f = 0; f < 4; f++)
            #pragma unroll
            for (int r = 0; r < 4; r++) mx = fmaxf(mx, accs[f][r]);
        mx = fmaxf(mx, __shfl_xor(mx, 16));
        mx = fmaxf(mx, __shfl_xor(mx, 32));

        const bool skip = __all(mx <= m_st);
        float corr = 1.f;
        if (!skip) {
            const float mnew = fmaxf(m_st, mx);
            corr = exp2f(m_st - mnew);
            m_st = mnew;
        }

        // ---- P = exp2(S - m), packed bf16 write (4x 8B per lane)
        float rs = 0.f;
        #pragma unroll
        for (int f = 0; f < 4; f++) {
            U16x4 pk;
            #pragma unroll
            for (int r = 0; r < 4; r++) {
                const float pv = exp2f(accs[f][r] - m_st);
                rs += pv;
                pk.v[r] = bf_bits((bf16)pv);
            }
            const int byte = q * 128 + ((32 * f + 8 * g) ^ ((q & 7) << 4));
            *(U16x4*)((char*)sP[w] + byte) = pk;
        }
        rs += __shfl_xor(rs, 16);
        rs += __shfl_xor(rs, 32);

        if (!skip) {
            l_st = l_st * corr + rs;
            #pragma unroll
            for (int r = 0; r < 4; r++) {
                const float cb = __shfl(corr, (g * 4 + r) + (l & 48));
                #pragma unroll
                for (int f = 0; f < 4; f++) acco[f][r] *= cb;
            }
        } else {
            l_st += rs;
        }

        asm volatile("s_waitcnt lgkmcnt(0)" ::: "memory");

        // ---- PV: A = P[q][kv] from sP, B = V^T rows (dv) from sV
        #pragma unroll
        for (int ks = 0; ks < 2; ks++) {
            bf16x8 ap = *(const bf16x8*)((const char*)sP[w] + q * 128 + ((ks * 64 + g * 16) ^ ((q & 7) << 4)));
            const int kb = g * 16 + ks * 64;
            #pragma unroll
            for (int f = 0; f < 4; f++) {
                const int vrow = q + 16 * f;   // dv row in LDS
                bf16x8 bv2 = *(const bf16x8*)((const char*)sV[buf] + vrow * 128 + (kb ^ ((vrow & 7) << 4)));
                acco[f] = mfma16(ap, bv2, acco[f]);
            }
        }
        __syncthreads();
    }

    if constexpr (NCHUNK == 1) {
        #pragma unroll
        for (int r = 0; r < 4; r++) {
            const float lb = __shfl(l_st, (g * 4 + r) + (l & 48));
            #pragma unroll
            for (int f = 0; f < 4; f++) {
                const int qrow = q0 + w * 16 + g * 4 + r;
                const int col  = 16 * f + q;
                out[((size_t)(b * 2048 + qrow)) * 64 + col] = acco[f][r] / lb;
            }
        }
    } else {
        // ---- write partials
        #pragma unroll
        for (int f = 0; f < 4; f++)
            #pragma unroll
            for (int r = 0; r < 4; r++) {
                const int qrow = q0 + w * 16 + g * 4 + r;
                const int col  = 16 * f + q;
                O_part[((size_t)c * 16384 + b * 2048 + qrow) * 64 + col] =
                    bf_bits((bf16)acco[f][r]);
            }
        if (l < 16) {
            const size_t idx = (size_t)c * 16384 + b * 2048 + q0 + w * 16 + l;
            m_arr[idx] = m_st;
            l_arr[idx] = l_st;
        }

        // ---- fastest-finisher combine
        __threadfence();
        if (t == 0)
            s_old = __hip_atomic_fetch_add(&cnt[b * 16 + qt], 1u,
                                           __ATOMIC_ACQ_REL, __HIP_MEMORY_SCOPE_AGENT);
        __syncthreads();
        if (s_old == NCHUNK - 1) {
            __threadfence();
            const int rl   = t >> 2;              // 0..127 local q-row
            const int coff = (t & 3) * 16;        // 16-col slice
            const size_t ridx = (size_t)b * 2048 + q0 + rl;
            float m[NCHUNK], lv[NCHUNK];
            #pragma unroll
            for (int c2 = 0; c2 < NCHUNK; c2++) {
                m[c2]  = m_arr[(size_t)c2 * 16384 + ridx];
                lv[c2] = l_arr[(size_t)c2 * 16384 + ridx];
            }
            float M = m[0];
            #pragma unroll
            for (int c2 = 1; c2 < NCHUNK; c2++) M = fmaxf(M, m[c2]);
            float L = 0.f, wgt[NCHUNK];
            #pragma unroll
            for (int c2 = 0; c2 < NCHUNK; c2++) {
                wgt[c2] = exp2f(m[c2] - M);
                L += lv[c2] * wgt[c2];
            }
            float accv[16];
            #pragma unroll
            for (int j = 0; j < 16; j++) accv[j] = 0.f;
            #pragma unroll
            for (int c2 = 0; c2 < NCHUNK; c2++) {
                const uint16_t* src = O_part + ((size_t)c2 * 16384 + ridx) * 64 + coff;
                U16x8 a0 = *(const U16x8*)src;
                U16x8 a1 = *(const U16x8*)(src + 8);
                #pragma unroll
                for (int j = 0; j < 8; j++) {
                    accv[j]     += bf2f(a0.v[j]) * wgt[c2];
                    accv[8 + j] += bf2f(a1.v[j]) * wgt[c2];
                }
            }
            const float invL = 1.f / L;
            float* dst = out + ridx * 64 + coff;
            #pragma unroll
            for (int j4 = 0; j4 < 4; j4++) {
                float4 o;
                o.x = accv[j4 * 4 + 0] * invL;
                o.y = accv[j4 * 4 + 1] * invL;
                o.z = accv[j4 * 4 + 2] * invL;
                o.w = accv[j4 * 4 + 3] * invL;
                *(float4*)(dst + j4 * 4) = o;
            }
        }
    }
}

// ---------------------------------------------------------------------------
extern "C" void kernel_launch(void* const* d_in, const int* in_sizes, int n_in,
                              void* d_out, int out_size, void* d_ws, size_t ws_size,
                              hipStream_t stream) {
    const float* xq = (const float*)d_in[0];
    const float* xk = (const float*)d_in[1];
    const float* xv = (const float*)d_in[2];
    const float* Wq = (const float*)d_in[3];
    const float* bq = (const float*)d_in[4];
    const float* Wk = (const float*)d_in[5];
    const float* bk = (const float*)d_in[6];
    const float* Wv = (const float*)d_in[7];
    const float* bv = (const float*)d_in[8];

    uint16_t* q_ws  = (uint16_t*)d_ws;
    uint16_t* k_ws  = q_ws + (size_t)16384 * 64;
    uint16_t* vt_ws = k_ws + (size_t)16384 * 64;
    uint16_t* O_part = vt_ws + (size_t)16384 * 64;              // bf16, 8.4 MB
    float* m_arr  = (float*)(O_part + (size_t)4 * 16384 * 64);
    float* l_arr  = m_arr + (size_t)4 * 16384;
    uint32_t* cnt = (uint32_t*)(l_arr + (size_t)4 * 16384);
    float* out = (float*)d_out;

    const size_t need = (size_t)3 * 16384 * 64 * 2            // q,k,vt bf16
                      + (size_t)4 * 16384 * 64 * 2            // O_part bf16
                      + (size_t)2 * 4 * 16384 * 4             // m,l
                      + 128 * 4;                              // counters

    proj_kernel<<<dim3(256, 3), 256, 0, stream>>>(xq, xk, xv, Wq, bq, Wk, bk, Wv, bv,
                                                  q_ws, k_ws, vt_ws, cnt);
    if (ws_size >= need) {
        attn_kernel<4><<<dim3(16, 8, 4), 512, 0, stream>>>(q_ws, k_ws, vt_ws, out,
                                                           O_part, m_arr, l_arr, cnt);
    } else {
        attn_kernel<1><<<dim3(16, 8, 1), 512, 0, stream>>>(q_ws, k_ws, vt_ws, out,
                                                           nullptr, nullptr, nullptr, nullptr);
    }
}

// Round 12
// 55.842 us; speedup vs baseline: 3.5137x; 3.5137x over previous
//
#include <hip/hip_runtime.h>
#include <stdint.h>

typedef __bf16 bf16;
typedef __bf16 bf16x8 __attribute__((ext_vector_type(8)));
typedef float f32x4 __attribute__((ext_vector_type(4)));

struct alignas(8) U16x4 { uint16_t v[4]; };

__device__ __forceinline__ f32x4 mfma16(bf16x8 a, bf16x8 b, f32x4 c) {
    return __builtin_amdgcn_mfma_f32_16x16x32_bf16(a, b, c, 0, 0, 0);
}

__device__ __forceinline__ void gload_lds16(const void* g, void* l) {
    __builtin_amdgcn_global_load_lds(
        (const __attribute__((address_space(1))) uint32_t*)g,
        (__attribute__((address_space(3))) uint32_t*)l, 16, 0, 0);
}

__device__ __forceinline__ uint16_t bf_bits(bf16 v) {
    return __builtin_bit_cast(uint16_t, v);
}

__device__ __forceinline__ float bf2f(uint16_t u) {
    uint32_t x = (uint32_t)u << 16;
    return __builtin_bit_cast(float, x);
}

// Q pre-scale: 1/sqrt(64) * log2(e), so attention works in exp2 domain.
#define QSCALE 0.18033688011112042f

// ---------------------------------------------------------------------------
// Projection: out = x @ W + b, W transposed f32->bf16 fragment-major into
// LDS in the prologue (W is tiny + L2-hot). BM=64, 256 threads (4 waves x
// 16 rows), grid 256x3 = 768 blocks = 3/CU. A-fragments direct from global
// with depth-8 static prefetch. q pre-scaled by QSCALE; v stored transposed.
// ---------------------------------------------------------------------------
__global__ __launch_bounds__(256, 2)
void proj_kernel(const float* __restrict__ xq, const float* __restrict__ xk,
                 const float* __restrict__ xv,
                 const float* __restrict__ Wq, const float* __restrict__ bq,
                 const float* __restrict__ Wk, const float* __restrict__ bk,
                 const float* __restrict__ Wv, const float* __restrict__ bv,
                 uint16_t* __restrict__ q_ws, uint16_t* __restrict__ k_ws,
                 uint16_t* __restrict__ vt_ws)
{
    const int p = blockIdx.y;
    const float* x    = (p == 0) ? xq : (p == 1) ? xk : xv;
    const float* W    = (p == 0) ? Wq : (p == 1) ? Wk : Wv;
    const float* bias = (p == 0) ? bq : (p == 1) ? bk : bv;

    const int m0 = blockIdx.x * 64;
    const int t  = threadIdx.x;
    const int l  = t & 63;
    const int w  = t >> 6;           // 0..3

    __shared__ __align__(16) uint16_t sW[32768];   // 64 KB: [kt][f][l] bf16x8

    const int arow = m0 + w * 16 + (l & 15);       // this lane's A-frag row
    const int kg   = (l >> 4) * 8;                 // k sub-offset in 32-step
    const float* xrow = x + (size_t)arow * 512 + kg;

    // ---- A prefetch prologue: depth 8 (16 loads in flight per lane)
    float4 av0[8], av1[8];
    #pragma unroll
    for (int s = 0; s < 8; s++) {
        av0[s] = *(const float4*)(xrow + s * 32);
        av1[s] = *(const float4*)(xrow + s * 32 + 4);
    }

    // ---- transpose W f32 -> bf16x8 fragments in LDS:
    // chunk index c = r*256 + t -> kt=r, f=(t>>6)&3, lane=t&63;
    // n=(lane&15)+16f, k0=kt*32+((lane>>4)&3)*8.
    {
        const int f2 = (t >> 6) & 3;
        const int n  = (t & 15) + 16 * f2;
        const int kq = ((t >> 4) & 3) * 8;
        #pragma unroll 4
        for (int r = 0; r < 16; r++) {
            const int k0 = r * 32 + kq;
            bf16x8 v;
            #pragma unroll
            for (int j = 0; j < 8; j++)
                v[j] = (bf16)W[(size_t)(k0 + j) * 64 + n];
            *(bf16x8*)((char*)sW + (r * 256 + t) * 16) = v;
        }
    }

    __syncthreads();

    f32x4 acc[4];
    const f32x4 zero = {0.f, 0.f, 0.f, 0.f};
    #pragma unroll
    for (int f = 0; f < 4; f++) acc[f] = zero;

    #pragma unroll
    for (int kt = 0; kt < 16; kt++) {
        const int slot = kt & 7;
        bf16x8 a;
        a[0] = (bf16)av0[slot].x; a[1] = (bf16)av0[slot].y;
        a[2] = (bf16)av0[slot].z; a[3] = (bf16)av0[slot].w;
        a[4] = (bf16)av1[slot].x; a[5] = (bf16)av1[slot].y;
        a[6] = (bf16)av1[slot].z; a[7] = (bf16)av1[slot].w;
        if (kt < 8) {
            const int kb = (kt + 8) * 32;
            av0[slot] = *(const float4*)(xrow + kb);
            av1[slot] = *(const float4*)(xrow + kb + 4);
        }
        #pragma unroll
        for (int f = 0; f < 4; f++) {
            bf16x8 bfr = *(const bf16x8*)((const char*)sW + ((kt * 4 + f) * 64 + l) * 16);
            acc[f] = mfma16(a, bfr, acc[f]);
        }
    }

    float bv4[4];
    #pragma unroll
    for (int f = 0; f < 4; f++) bv4[f] = bias[16 * f + (l & 15)];

    if (p < 2) {
        uint16_t* outp = (p == 0) ? q_ws : k_ws;
        const float scale = (p == 0) ? QSCALE : 1.0f;
        #pragma unroll
        for (int f = 0; f < 4; f++)
            #pragma unroll
            for (int r = 0; r < 4; r++) {
                const int row = m0 + w * 16 + (l >> 4) * 4 + r;
                const int col = 16 * f + (l & 15);
                outp[(size_t)row * 64 + col] = bf_bits((bf16)((acc[f][r] + bv4[f]) * scale));
            }
    } else {
        #pragma unroll
        for (int f = 0; f < 4; f++) {
            const int row0 = m0 + w * 16 + (l >> 4) * 4;
            const int col  = 16 * f + (l & 15);
            const int bb = row0 >> 11;
            const int s0 = row0 & 2047;
            U16x4 pk;
            #pragma unroll
            for (int r = 0; r < 4; r++)
                pk.v[r] = bf_bits((bf16)(acc[f][r] + bv4[f]));
            *(U16x4*)(vt_ws + ((size_t)bb * 64 + col) * 2048 + s0) = pk;
        }
    }
}

// ---------------------------------------------------------------------------
// Flash attention, SWAPPED QK^T (lane holds S[kv][q]; softmax = 15 reg-max +
// 2 shfl). NCHUNK=4: grid (16,8,4)=512 blocks. KV tiles of 64, double-
// buffered gload_lds with pre-swizzled source. Exact defer-rescale.
// NCHUNK>1: writes bf16 O_part + (m,l) f32; combine_kernel merges.
// ---------------------------------------------------------------------------
template <int NCHUNK>
__global__ __launch_bounds__(512, 4)
void attn_kernel(const uint16_t* __restrict__ q_ws, const uint16_t* __restrict__ k_ws,
                 const uint16_t* __restrict__ vt_ws, float* __restrict__ out,
                 uint16_t* __restrict__ O_part, float* __restrict__ m_arr,
                 float* __restrict__ l_arr)
{
    constexpr int NT = 32 / NCHUNK;  // KV tiles per chunk
    const int qt = blockIdx.x, b = blockIdx.y, c = blockIdx.z;
    const int t = threadIdx.x, l = t & 63, w = t >> 6;   // w: 0..7
    const int q = l & 15, g = l >> 4;
    const int q0 = qt * 128;

    __shared__ __align__(16) uint16_t sK[2][64 * 64];  // [s][d] swizzled
    __shared__ __align__(16) uint16_t sV[2][64 * 64];  // [dv][s] swizzled
    __shared__ __align__(16) uint16_t sP[8][16 * 64];  // per-wave P [q][kv], swizzled

    const uint16_t* qp = q_ws + ((size_t)(b * 2048 + q0)) * 64;
    const uint16_t* kp = k_ws + (size_t)b * 2048 * 64;
    const uint16_t* vp = vt_ws + (size_t)b * 64 * 2048;

    // Q fragments (pre-scaled: scores come out in log2 units)
    bf16x8 aq[2];
    #pragma unroll
    for (int ks = 0; ks < 2; ks++)
        aq[ks] = *(const bf16x8*)(qp + (size_t)(w * 16 + q) * 64 + g * 8 + ks * 32);

    const f32x4 zero = {0.f, 0.f, 0.f, 0.f};
    f32x4 acco[4];
    #pragma unroll
    for (int f = 0; f < 4; f++) acco[f] = zero;
    float m_st = -__builtin_inff();   // running max for this q-row
    float l_st = 0.f;                 // running sum for this q-row

    // 512 threads: thread t stages one 16B chunk of K and one of V.
    auto stage = [&](int tile, int buf) {
        const int kv0  = tile * 64;
        const int row  = t >> 3;                    // 0..63
        const int slot = (t & 7) ^ (row & 7);       // inverse swizzle on source
        gload_lds16(kp + (size_t)(kv0 + row) * 64 + slot * 8,
                    (char*)sK[buf] + t * 16);
        gload_lds16(vp + (size_t)row * 2048 + kv0 + slot * 8,
                    (char*)sV[buf] + t * 16);
    };

    stage(c * NT, 0);
    __syncthreads();

    for (int i = 0; i < NT; i++) {
        const int buf = i & 1;
        if (i < NT - 1) stage(c * NT + i + 1, buf ^ 1);

        // ---- scores, swapped: accs[f][r] = S[kv=f*16+g*4+r][q]  (log2 dom.)
        f32x4 accs[4];
        #pragma unroll
        for (int f = 0; f < 4; f++) accs[f] = zero;
        #pragma unroll
        for (int ks = 0; ks < 2; ks++) {
            const int kb = g * 16 + ks * 64;
            #pragma unroll
            for (int f = 0; f < 4; f++) {
                const int srow = q + 16 * f;   // kv row in LDS
                bf16x8 bk = *(const bf16x8*)((const char*)sK[buf] + srow * 128 + (kb ^ ((srow & 7) << 4)));
                accs[f] = mfma16(bk, aq[ks], accs[f]);   // A=K, B=Q
            }
        }

        // ---- per-lane softmax over 16 regs + 4-lane butterfly
        float mx = accs[0][0];
        #pragma unroll
        for (int f = 0; f < 4; f++)
            #pragma unroll
            for (int r = 0; r < 4; r++) mx = fmaxf(mx, accs[f][r]);
        mx = fmaxf(mx, __shfl_xor(mx, 16));
        mx = fmaxf(mx, __shfl_xor(mx, 32));

        const bool skip = __all(mx <= m_st);
        float corr = 1.f;
        if (!skip) {
            const float mnew = fmaxf(m_st, mx);
            corr = exp2f(m_st - mnew);
            m_st = mnew;
        }

        // ---- P = exp2(S - m), packed bf16 write (4x 8B per lane)
        float rs = 0.f;
        #pragma unroll
        for (int f = 0; f < 4; f++) {
            U16x4 pk;
            #pragma unroll
            for (int r = 0; r < 4; r++) {
                const float pv = exp2f(accs[f][r] - m_st);
                rs += pv;
                pk.v[r] = bf_bits((bf16)pv);
            }
            const int byte = q * 128 + ((32 * f + 8 * g) ^ ((q & 7) << 4));
            *(U16x4*)((char*)sP[w] + byte) = pk;
        }
        rs += __shfl_xor(rs, 16);
        rs += __shfl_xor(rs, 32);

        if (!skip) {
            l_st = l_st * corr + rs;
            #pragma unroll
            for (int r = 0; r < 4; r++) {
                const float cb = __shfl(corr, (g * 4 + r) + (l & 48));
                #pragma unroll
                for (int f = 0; f < 4; f++) acco[f][r] *= cb;
            }
        } else {
            l_st += rs;
        }

        asm volatile("s_waitcnt lgkmcnt(0)" ::: "memory");

        // ---- PV: A = P[q][kv] from sP, B = V^T rows (dv) from sV
        #pragma unroll
        for (int ks = 0; ks < 2; ks++) {
            bf16x8 ap = *(const bf16x8*)((const char*)sP[w] + q * 128 + ((ks * 64 + g * 16) ^ ((q & 7) << 4)));
            const int kb = g * 16 + ks * 64;
            #pragma unroll
            for (int f = 0; f < 4; f++) {
                const int vrow = q + 16 * f;   // dv row in LDS
                bf16x8 bv2 = *(const bf16x8*)((const char*)sV[buf] + vrow * 128 + (kb ^ ((vrow & 7) << 4)));
                acco[f] = mfma16(ap, bv2, acco[f]);
            }
        }
        __syncthreads();
    }

    if constexpr (NCHUNK == 1) {
        #pragma unroll
        for (int r = 0; r < 4; r++) {
            const float lb = __shfl(l_st, (g * 4 + r) + (l & 48));
            #pragma unroll
            for (int f = 0; f < 4; f++) {
                const int qrow = q0 + w * 16 + g * 4 + r;
                const int col  = 16 * f + q;
                out[((size_t)(b * 2048 + qrow)) * 64 + col] = acco[f][r] / lb;
            }
        }
    } else {
        #pragma unroll
        for (int f = 0; f < 4; f++)
            #pragma unroll
            for (int r = 0; r < 4; r++) {
                const int qrow = q0 + w * 16 + g * 4 + r;
                const int col  = 16 * f + q;
                O_part[((size_t)c * 16384 + b * 2048 + qrow) * 64 + col] =
                    bf_bits((bf16)acco[f][r]);
            }
        if (l < 16) {
            const size_t idx = (size_t)c * 16384 + b * 2048 + q0 + w * 16 + l;
            m_arr[idx] = m_st;
            l_arr[idx] = l_st;
        }
    }
}

// ---------------------------------------------------------------------------
// Combine: merge NCHUNK=4 bf16 partials (exp2-domain m). Grid (128, 8).
// ---------------------------------------------------------------------------
__global__ __launch_bounds__(256, 8)
void combine_kernel(const uint16_t* __restrict__ O_part, const float* __restrict__ m_arr,
                    const float* __restrict__ l_arr, float* __restrict__ out)
{
    const int b = blockIdx.y;
    const int r0 = (blockIdx.x >> 2) * 64 + (blockIdx.x & 3) * 16;
    const int t = threadIdx.x;
    const int col = t & 63;
    const int rg = t >> 6;

    #pragma unroll
    for (int pass = 0; pass < 4; pass++) {
        const int qrow = r0 + pass * 4 + rg;
        const size_t ridx = (size_t)b * 2048 + qrow;
        float m[4], lv[4];
        #pragma unroll
        for (int c = 0; c < 4; c++) {
            m[c]  = m_arr[(size_t)c * 16384 + ridx];
            lv[c] = l_arr[(size_t)c * 16384 + ridx];
        }
        const float M = fmaxf(fmaxf(m[0], m[1]), fmaxf(m[2], m[3]));
        float L = 0.f, wgt[4];
        #pragma unroll
        for (int c = 0; c < 4; c++) { wgt[c] = exp2f(m[c] - M); L += lv[c] * wgt[c]; }
        float acc = 0.f;
        #pragma unroll
        for (int c = 0; c < 4; c++)
            acc += bf2f(O_part[((size_t)c * 16384 + ridx) * 64 + col]) * wgt[c];
        out[ridx * 64 + col] = acc / L;
    }
}

// ---------------------------------------------------------------------------
extern "C" void kernel_launch(void* const* d_in, const int* in_sizes, int n_in,
                              void* d_out, int out_size, void* d_ws, size_t ws_size,
                              hipStream_t stream) {
    const float* xq = (const float*)d_in[0];
    const float* xk = (const float*)d_in[1];
    const float* xv = (const float*)d_in[2];
    const float* Wq = (const float*)d_in[3];
    const float* bq = (const float*)d_in[4];
    const float* Wk = (const float*)d_in[5];
    const float* bk = (const float*)d_in[6];
    const float* Wv = (const float*)d_in[7];
    const float* bv = (const float*)d_in[8];

    uint16_t* q_ws  = (uint16_t*)d_ws;
    uint16_t* k_ws  = q_ws + (size_t)16384 * 64;
    uint16_t* vt_ws = k_ws + (size_t)16384 * 64;
    uint16_t* O_part = vt_ws + (size_t)16384 * 64;              // bf16, 8.4 MB
    float* m_arr  = (float*)(O_part + (size_t)4 * 16384 * 64);
    float* l_arr  = m_arr + (size_t)4 * 16384;
    float* out = (float*)d_out;

    const size_t need = (size_t)3 * 16384 * 64 * 2            // q,k,vt bf16
                      + (size_t)4 * 16384 * 64 * 2            // O_part bf16
                      + (size_t)2 * 4 * 16384 * 4;            // m,l

    proj_kernel<<<dim3(256, 3), 256, 0, stream>>>(xq, xk, xv, Wq, bq, Wk, bk, Wv, bv,
                                                  q_ws, k_ws, vt_ws);
    if (ws_size >= need) {
        attn_kernel<4><<<dim3(16, 8, 4), 512, 0, stream>>>(q_ws, k_ws, vt_ws, out,
                                                           O_part, m_arr, l_arr);
        combine_kernel<<<dim3(128, 8), 256, 0, stream>>>(O_part, m_arr, l_arr, out);
    } else {
        attn_kernel<1><<<dim3(16, 8, 1), 512, 0, stream>>>(q_ws, k_ws, vt_ws, out,
                                                           nullptr, nullptr, nullptr);
    }
}